// Round 9
// baseline (672.127 us; speedup 1.0000x reference)
//
#include <hip/hip_runtime.h>
#include <stdint.h>

typedef unsigned short ushort_t;
typedef __bf16 bf16x8 __attribute__((ext_vector_type(8)));
typedef float f32x4 __attribute__((ext_vector_type(4)));
typedef ushort_t us4 __attribute__((ext_vector_type(4)));

#define MFMA16(a, b, c) __builtin_amdgcn_mfma_f32_16x16x32_bf16((a), (b), (c), 0, 0, 0)

constexpr int Bn = 4, Sn = 2048, Dn = 1024, Hn = 16, HDn = 64;
constexpr float SCALE = 0.125f;   // 1/sqrt(64)
constexpr float NEG = -1e9f;

__device__ __forceinline__ ushort_t f2bf(float f) {
  unsigned x = __builtin_bit_cast(unsigned, f);
  x = x + 0x7FFFu + ((x >> 16) & 1u);   // RNE
  return (ushort_t)(x >> 16);
}
// 8 x f32 -> bf16x8 via compiler (v_cvt_pk_bf16_f32, RNE — same bits as f2bf)
__device__ __forceinline__ bf16x8 cvt8(float4 a, float4 b) {
  bf16x8 r;
  r[0] = (__bf16)a.x; r[1] = (__bf16)a.y; r[2] = (__bf16)a.z; r[3] = (__bf16)a.w;
  r[4] = (__bf16)b.x; r[5] = (__bf16)b.y; r[6] = (__bf16)b.z; r[7] = (__bf16)b.w;
  return r;
}
__device__ __forceinline__ uint4 ld8_f32_bf16(const float* __restrict__ p) {
  float4 a = *(const float4*)p;
  float4 b = *(const float4*)(p + 4);
  union { ushort_t u[8]; uint4 v; } r;
  r.u[0] = f2bf(a.x); r.u[1] = f2bf(a.y); r.u[2] = f2bf(a.z); r.u[3] = f2bf(a.w);
  r.u[4] = f2bf(b.x); r.u[5] = f2bf(b.y); r.u[6] = f2bf(b.z); r.u[7] = f2bf(b.w);
  return r.v;
}
// async global->LDS, 16B per lane; LDS dest = wave-uniform base + lane*16
__device__ __forceinline__ void gl2lds16(const void* g, void* l) {
  __builtin_amdgcn_global_load_lds(
      (__attribute__((address_space(1))) void*)g,
      (__attribute__((address_space(3))) void*)l, 16, 0, 0);
}

// Fused Q/K/V projections consuming f32 X AND f32 W directly (no cvt pass).
// Both operands reg-staged: per K-step each thread loads 32B f32 of one
// A-row and one B-row, converts via v_cvt_pk_bf16_f32 (RNE - bit-identical
// to the old cvt_all+bf16 path) and ds_write_b128's into the SAME swizzled
// bf16 LDS layout as before -> MFMA read path untouched, LDS 32 KB,
// 4 blocks/CU. Next-step loads issued under the MFMA phase (T14).
// z = 0/1/2 selects X, W, bias, dst, epilogue; z=2 also emits per-tile V
// row-sums R (f32, no atomics, quad-lane shfl).
__global__ __launch_bounds__(256, 4)
void qkv_f32(const float* __restrict__ xq, const float* __restrict__ xk,
             const float* __restrict__ xv, const float* __restrict__ wq,
             const float* __restrict__ wk, const float* __restrict__ wv,
             const float* __restrict__ bq, const float* __restrict__ bk,
             const float* __restrict__ bv, ushort_t* __restrict__ Qd,
             ushort_t* __restrict__ Ktd, ushort_t* __restrict__ Vtd,
             float* __restrict__ Rs) {
  constexpr int K = 1024;
  __shared__ __align__(16) ushort_t As[128 * 64];
  __shared__ __align__(16) ushort_t Bs[128 * 64];

  const int z = blockIdx.z;
  const float* A  = z == 0 ? xq : z == 1 ? xk : xv;
  const float* Wf = z == 0 ? wq : z == 1 ? wk : wv;
  const float* bias = z == 0 ? bq : z == 1 ? bk : bv;
  ushort_t* Cp = z == 0 ? Qd : z == 1 ? Ktd : Vtd;

  const int tid = threadIdx.x;
  const int lane = tid & 63, w = tid >> 6;
  const int quad = lane >> 4, l16 = lane & 15;
  const int wm = w >> 1, wn = w & 1;
  const int row0 = blockIdx.x * 128;   // x = row (XCD co-location)
  const int col0 = blockIdx.y * 128;   // y = col

  // staging map: lane -> row (w*32 + i*8 + (lane>>3)), f32 cols (lane&7)*8..+8
  // dest granule (lane&7)^(row&7) is lane-constant since i*8 ≡ 0 (mod 8).
  const int ar = lane >> 3;
  const int ac = (lane & 7) * 8;
  const float* Af = A  + (size_t)(row0 + w * 32 + ar) * K + ac;
  const float* Bf = Wf + (size_t)(col0 + w * 32 + ar) * K + ac;
  ushort_t* Adst = &As[(w * 32 + ar) * 64 + (((lane & 7) ^ (ar & 7)) * 8)];
  ushort_t* Bdst = &Bs[(w * 32 + ar) * 64 + (((lane & 7) ^ (ar & 7)) * 8)];

  float4 a0[4], a1[4], b0[4], b1[4];
#pragma unroll
  for (int i = 0; i < 4; ++i) {        // prologue: k0 = 0 loads
    const float* sa = Af + (size_t)(i * 8) * K;
    const float* sb = Bf + (size_t)(i * 8) * K;
    a0[i] = *(const float4*)sa; a1[i] = *(const float4*)(sa + 4);
    b0[i] = *(const float4*)sb; b1[i] = *(const float4*)(sb + 4);
  }

  f32x4 acc[4][4] = {};

  for (int k0 = 0; k0 < K; k0 += 64) {
    __syncthreads();                   // previous compute done, LDS free
#pragma unroll
    for (int i = 0; i < 4; ++i) {
      *(bf16x8*)(Adst + i * 8 * 64) = cvt8(a0[i], a1[i]);
      *(bf16x8*)(Bdst + i * 8 * 64) = cvt8(b0[i], b1[i]);
    }
    __syncthreads();                   // ds_writes visible

    if (k0 + 64 < K) {                 // next-step loads fly under compute
#pragma unroll
      for (int i = 0; i < 4; ++i) {
        const float* sa = Af + (size_t)(i * 8) * K + (k0 + 64);
        const float* sb = Bf + (size_t)(i * 8) * K + (k0 + 64);
        a0[i] = *(const float4*)sa; a1[i] = *(const float4*)(sa + 4);
        b0[i] = *(const float4*)sb; b1[i] = *(const float4*)(sb + 4);
      }
    }

#pragma unroll
    for (int ks = 0; ks < 2; ++ks) {
      const int kg = ((ks * 4 + quad) ^ (l16 & 7)) * 8;
      bf16x8 af[4], bfr[4];
#pragma unroll
      for (int mt = 0; mt < 4; ++mt)
        af[mt] = *(const bf16x8*)(&As[(wm * 64 + mt * 16 + l16) * 64 + kg]);
#pragma unroll
      for (int nt = 0; nt < 4; ++nt)
        bfr[nt] = *(const bf16x8*)(&Bs[(wn * 64 + nt * 16 + l16) * 64 + kg]);
#pragma unroll
      for (int mt = 0; mt < 4; ++mt)
#pragma unroll
        for (int nt = 0; nt < 4; ++nt)
          acc[mt][nt] = MFMA16(af[mt], bfr[nt], acc[mt][nt]);
    }
  }

#pragma unroll
  for (int mt = 0; mt < 4; ++mt) {
#pragma unroll
    for (int nt = 0; nt < 4; ++nt) {
      const int col = col0 + wn * 64 + nt * 16 + l16;
      const float bv4 = bias[col];
      const int rowb = row0 + wm * 64 + mt * 16 + quad * 4;
      if (z != 0) {          // transposed scatter: [b,h,hd,s], b64 over s
        const int b = rowb >> 11, s = rowb & (Sn - 1);
        const int h = col >> 6, hd = col & 63;
        us4 pk;
#pragma unroll
        for (int r = 0; r < 4; ++r) pk[r] = f2bf(acc[mt][nt][r] + bv4);
        *(us4*)(Cp + ((size_t)((b * Hn + h) * HDn + hd)) * Sn + s) = pk;
      } else {               // Q scatter: [b,h,s,hd]
#pragma unroll
        for (int r = 0; r < 4; ++r) {
          const int row = rowb + r;
          const int b = row >> 11, s = row & (Sn - 1);
          const int h = col >> 6, hd = col & 63;
          Cp[(((size_t)(b * Hn + h) * Sn + s) << 6) + hd] = f2bf(acc[mt][nt][r] + bv4);
        }
      }
    }
  }

  if (z == 2) {   // V tile row-sums: R[bh][t][n], t = wm-half (full 64 rows)
    const int b = row0 >> 11;
    const int t = ((row0 & (Sn - 1)) >> 6) + wm;
#pragma unroll
    for (int nt = 0; nt < 4; ++nt) {
      const int col = col0 + wn * 64 + nt * 16 + l16;
      const float bv4 = bias[col];
      float p = 0.f;
#pragma unroll
      for (int mt = 0; mt < 4; ++mt)
#pragma unroll
        for (int r = 0; r < 4; ++r) p += acc[mt][nt][r] + bv4;
      p += __shfl_xor(p, 16);
      p += __shfl_xor(p, 32);
      if (quad == 0) {
        const int h = col >> 6, n = col & 63;
        Rs[((size_t)(b * Hn + h) * 32 + t) * 64 + n] = p;
      }
    }
  }
}

// Final projection: C[M,N] f32 = A[M,K]bf16 @ W[N,K]^T + bias.
__global__ __launch_bounds__(256, 4)
void gemm_out(const ushort_t* __restrict__ A, const ushort_t* __restrict__ Wt,
              const float* __restrict__ bias, float* __restrict__ Cp) {
  constexpr int K = 1024;
  __shared__ __align__(16) ushort_t As[128 * 64];
  __shared__ __align__(16) ushort_t Bs[128 * 64];

  const int tid = threadIdx.x;
  const int lane = tid & 63, w = tid >> 6;
  const int quad = lane >> 4, l16 = lane & 15;
  const int wm = w >> 1, wn = w & 1;
  const int row0 = blockIdx.x * 128;
  const int col0 = blockIdx.y * 128;

  const int sr = lane >> 3;
  const int sg = ((lane & 7) ^ (sr & 7)) * 8;
  const ushort_t* Ab = A  + (size_t)(row0 + w * 32 + sr) * K + sg;
  const ushort_t* Bb = Wt + (size_t)(col0 + w * 32 + sr) * K + sg;

  f32x4 acc[4][4] = {};

  for (int k0 = 0; k0 < K; k0 += 64) {
    __syncthreads();
#pragma unroll
    for (int i = 0; i < 4; ++i) {
      gl2lds16(Ab + (size_t)(i * 8) * K + k0, &As[(w * 32 + i * 8) * 64]);
      gl2lds16(Bb + (size_t)(i * 8) * K + k0, &Bs[(w * 32 + i * 8) * 64]);
    }
    __syncthreads();
#pragma unroll
    for (int ks = 0; ks < 2; ++ks) {
      const int kg = ((ks * 4 + quad) ^ (l16 & 7)) * 8;
      bf16x8 af[4], bfr[4];
#pragma unroll
      for (int mt = 0; mt < 4; ++mt)
        af[mt] = *(const bf16x8*)(&As[(wm * 64 + mt * 16 + l16) * 64 + kg]);
#pragma unroll
      for (int nt = 0; nt < 4; ++nt)
        bfr[nt] = *(const bf16x8*)(&Bs[(wn * 64 + nt * 16 + l16) * 64 + kg]);
#pragma unroll
      for (int mt = 0; mt < 4; ++mt)
#pragma unroll
        for (int nt = 0; nt < 4; ++nt)
          acc[mt][nt] = MFMA16(af[mt], bfr[nt], acc[mt][nt]);
    }
  }

#pragma unroll
  for (int mt = 0; mt < 4; ++mt)
#pragma unroll
    for (int nt = 0; nt < 4; ++nt) {
      const int col = col0 + wn * 64 + nt * 16 + l16;
      const float bv = bias[col];
      const int rowb = row0 + wm * 64 + mt * 16 + quad * 4;
#pragma unroll
      for (int r = 0; r < 4; ++r)
        Cp[(size_t)(rowb + r) * 1024 + col] = acc[mt][nt][r] + bv;
    }
}

// Self-prefix attention + Wo conversion preamble (512 blocks x 256 thr x
// 8 elems = exactly |Wo|; hides under the prefix stream; gemm_out consumes
// the bf16 Wo next dispatch). Grid (x=bh 64, y=g 8). LDS 50 KB (Zs aliased
// onto prefix buffer Kp1) -> 3 blocks/CU.
__global__ __launch_bounds__(256)
void scan_attn2(const ushort_t* __restrict__ Q, const ushort_t* __restrict__ Kt,
                const ushort_t* __restrict__ Vt, const float* __restrict__ Rs,
                const float* __restrict__ wo, ushort_t* __restrict__ WoB,
                ushort_t* __restrict__ O) {
  // [0,8192) Kp0 (prefix dbuf 0; diag-K A-layout in attn)
  // [8192,16384) Kp1 (prefix dbuf 1) / Zs (attn)
  // [16384,32768) Vts[2]   [32768,40960) Ks
  // [40960,50176) Ss[64][72]   [50176,51200) sfx[4][64]
  __shared__ __align__(16) char smem[51200];
  ushort_t* KpB  = (ushort_t*)smem;
  ushort_t* Zs   = (ushort_t*)(smem + 8192);
  ushort_t* VtsB = (ushort_t*)(smem + 16384);
  ushort_t* Ks   = (ushort_t*)(smem + 32768);
  ushort_t (*Ss)[72] = (ushort_t(*)[72])(smem + 40960);
  float (*sfx)[64] = (float(*)[64])(smem + 50176);

  const int tid = threadIdx.x, lane = tid & 63, w = tid >> 6;
  const int quad = lane >> 4, l16 = lane & 15;
  const int bh = blockIdx.x;           // 0..63
  const int g = blockIdx.y;            // 0..7, q-tiles 4g..4g+3
  const int qt0 = g * 4;
  const int b = bh >> 4, h = bh & 15;
  const ushort_t* Qb  = Q  + (size_t)bh * Sn * HDn;
  const ushort_t* Ktb = Kt + (size_t)bh * HDn * Sn;
  const ushort_t* Vtb = Vt + (size_t)bh * HDn * Sn;
  const float* Rb = Rs + (size_t)bh * 32 * 64;

  const int sr = lane >> 3;
  const int sg = ((lane & 7) ^ (sr & 7)) * 8;
  const int q8 = lane & 7, h8 = lane >> 3;

  // Wo f32 -> bf16 (this block's 1/512 slice)
  {
    const size_t i = ((size_t)(bh * 8 + g) * 256 + tid) * 8;
    *(uint4*)(WoB + i) = ld8_f32_bf16(wo + i);
  }

  // ---- prefix phase: pzacc = sum_{tau<qt0} K_tau (x) V_tau (MFMA C-layout:
  // pzacc[nt][r] = Z[d = w*16+quad*4+r][n = nt*16+l16]) ----
  f32x4 pzacc[4] = {};
  if (qt0 > 0) {
#pragma unroll
    for (int c = 0; c < 2; ++c) {
      const int row = w * 16 + c * 8;
      gl2lds16(Ktb + (size_t)(row + sr) * Sn + sg, &KpB[row * 64]);
      gl2lds16(Vtb + (size_t)(row + sr) * Sn + sg, &VtsB[row * 64]);
    }
    for (int tau = 0; tau < qt0; ++tau) {
      const int pc = tau & 1;
      __syncthreads();                 // staging of buf[pc] drained
      if (tau + 1 < qt0) {             // prefetch tau+1 into other buffer
#pragma unroll
        for (int c = 0; c < 2; ++c) {
          const int row = w * 16 + c * 8;
          gl2lds16(Ktb + (size_t)(row + sr) * Sn + (tau + 1) * 64 + sg,
                   &KpB[(1 - pc) * 4096 + row * 64]);
          gl2lds16(Vtb + (size_t)(row + sr) * Sn + (tau + 1) * 64 + sg,
                   &VtsB[(1 - pc) * 4096 + row * 64]);
        }
      }
#pragma unroll
      for (int ks = 0; ks < 2; ++ks) {
        const int kg = ((ks * 4 + quad) ^ (l16 & 7)) * 8;
        bf16x8 ak = *(const bf16x8*)(&KpB[pc * 4096 + (w * 16 + l16) * 64 + kg]);
#pragma unroll
        for (int nt = 0; nt < 4; ++nt) {
          bf16x8 bv8 = *(const bf16x8*)(&VtsB[pc * 4096 + (nt * 16 + l16) * 64 + kg]);
          pzacc[nt] = MFMA16(ak, bv8, pzacc[nt]);
        }
      }
    }
    __syncthreads();                   // last prefix reads done before reuse
  }

  // ---- attn prologue: stage q-tile qt0 ----
  uint4  kvr[2][2];
  bf16x8 bqr[2][2];
  {
    const int q0 = qt0 * 64;
#pragma unroll
    for (int c = 0; c < 2; ++c) {
      const int row = w * 16 + c * 8;
      gl2lds16(Vtb + (size_t)(row + sr) * Sn + q0 + sg, &VtsB[row * 64]);
      kvr[0][c] = *(const uint4*)(Ktb + (size_t)(w * 16 + c * 8 + h8) * Sn + q0 + q8 * 8);
    }
#pragma unroll
    for (int ks = 0; ks < 2; ++ks)
      bqr[0][ks] = *(const bf16x8*)(Qb + (size_t)(q0 + w * 16 + l16) * HDn + (ks * 4 + quad) * 8);
  }

  // local suffix-V: sfx[i][n] = sum_{tau > qt0+i} R[tau][n]
  if (tid < 64) {
    float acc = 0.f;
    for (int tau = 31; tau >= qt0; --tau) {
      if (tau < qt0 + 4) sfx[tau - qt0][tid] = acc;
      acc += Rb[(size_t)tau * 64 + tid];
    }
  }

#pragma unroll 4
  for (int i = 0; i < 4; ++i) {
    const int cur = i & 1;
    const int qt = qt0 + i, q0 = qt * 64;

    __syncthreads();   // B1: compute i-1 done (Zs/Ks/Kp0 free); i=0: sfx cover

    // write Z for this q-tile from pzacc (MFMA layout) into swizzled Zs[n][d]
#pragma unroll
    for (int nt = 0; nt < 4; ++nt) {
      const int n = nt * 16 + l16;
      const int d0 = w * 16 + quad * 4;
      us4 pk;
#pragma unroll
      for (int r = 0; r < 4; ++r) pk[r] = f2bf(SCALE * pzacc[nt][r]);
      *(us4*)(&Zs[n * 64 + (((d0 >> 3) ^ (n & 7)) << 3) + (d0 & 7)]) = pk;
    }
    // transpose-write diagonal K tile (regs -> Ks, rotated+swizzled)
#pragma unroll
    for (int c = 0; c < 2; ++c) {
      const int hd = w * 16 + c * 8 + h8;
      const int G = hd >> 3;
      const ushort_t* ku = (const ushort_t*)&kvr[cur][c];
#pragma unroll
      for (int j = 0; j < 8; ++j) {
        const int e = (j + q8) & 7;
        const int s = q8 * 8 + e;
        Ks[s * 64 + ((G ^ e) << 3) + (hd & 7)] = ku[e];
      }
    }
    // diag K ALSO in standard A-layout (for the Z advance): Kp0
#pragma unroll
    for (int c = 0; c < 2; ++c) {
      const int hd = w * 16 + c * 8 + h8;
      *(uint4*)(&KpB[hd * 64 + ((q8 ^ (hd & 7)) << 3)]) = kvr[cur][c];
    }

    __syncthreads();   // B2: ds_writes visible + V(qt) staging drained

    if (i < 3) {       // issue next-tile loads; fly under compute(i)
      const int q1 = (qt + 1) * 64, nxt = 1 - cur;
#pragma unroll
      for (int c = 0; c < 2; ++c) {
        const int row = w * 16 + c * 8;
        gl2lds16(Vtb + (size_t)(row + sr) * Sn + q1 + sg, &VtsB[nxt * 4096 + row * 64]);
        kvr[nxt][c] = *(const uint4*)(Ktb + (size_t)(w * 16 + c * 8 + h8) * Sn + q1 + q8 * 8);
      }
#pragma unroll
      for (int ks = 0; ks < 2; ++ks)
        bqr[nxt][ks] = *(const bf16x8*)(Qb + (size_t)(q1 + w * 16 + l16) * HDn + (ks * 4 + quad) * 8);
    }

    // ---- compute q-tile qt ----
    f32x4 oacc[4] = {};
#pragma unroll
    for (int ks = 0; ks < 2; ++ks) {        // prefix: O^T += Z' · Q^T
      const int kg = ((ks * 4 + quad) ^ (l16 & 7)) * 8;
#pragma unroll
      for (int nt = 0; nt < 4; ++nt) {
        bf16x8 az = *(const bf16x8*)(&Zs[(nt * 16 + l16) * 64 + kg]);
        oacc[nt] = MFMA16(az, bqr[cur][ks], oacc[nt]);
      }
    }
    f32x4 sacc[4] = {};
#pragma unroll
    for (int ks = 0; ks < 2; ++ks) {        // diagonal: S^T = K_d · Q^T
      const int kg = ((ks * 4 + quad) ^ (l16 & 7)) * 8;
#pragma unroll
      for (int nt = 0; nt < 4; ++nt) {
        bf16x8 ak = *(const bf16x8*)(&Ks[(nt * 16 + l16) * 64 + kg]);
        sacc[nt] = MFMA16(ak, bqr[cur][ks], sacc[nt]);
      }
    }
    const int qrel = w * 16 + l16;          // mask + scale -> Ss (b64, intra-wave)
#pragma unroll
    for (int nt = 0; nt < 4; ++nt) {
      const int kb = nt * 16 + quad * 4;
      us4 pk;
#pragma unroll
      for (int r = 0; r < 4; ++r) {
        float val = (kb + r > qrel) ? NEG : sacc[nt][r] * SCALE;
        pk[r] = f2bf(val);
      }
      *(us4*)(&Ss[qrel][kb]) = pk;
    }
#pragma unroll
    for (int ks = 0; ks < 2; ++ks) {        // O^T += V_d^T · S_d^T
      bf16x8 bs = *(const bf16x8*)(&Ss[qrel][ks * 32 + quad * 8]);
#pragma unroll
      for (int nt = 0; nt < 4; ++nt) {
        bf16x8 av = *(const bf16x8*)(&VtsB[cur * 4096 + (nt * 16 + l16) * 64 + (((ks * 4 + quad) ^ (l16 & 7)) << 3)]);
        oacc[nt] = MFMA16(av, bs, oacc[nt]);
      }
    }

    // masked tail + store O[b,s,d] (b64 over n)
    const int s = q0 + w * 16 + l16;
#pragma unroll
    for (int nt = 0; nt < 4; ++nt) {
      const int nb = nt * 16 + quad * 4;
      float4 s4 = *(const float4*)(&sfx[i][nb]);
      us4 pk;
      pk[0] = f2bf(oacc[nt][0] + NEG * s4.x);
      pk[1] = f2bf(oacc[nt][1] + NEG * s4.y);
      pk[2] = f2bf(oacc[nt][2] + NEG * s4.z);
      pk[3] = f2bf(oacc[nt][3] + NEG * s4.w);
      *(us4*)(&O[((size_t)(b * Sn + s)) * Dn + h * 64 + nb]) = pk;
    }

    if (i < 3) {   // advance prefix: pzacc += K_qt (x) V_qt (diag tile)
#pragma unroll
      for (int ks = 0; ks < 2; ++ks) {
        const int kg = ((ks * 4 + quad) ^ (l16 & 7)) * 8;
        bf16x8 ak = *(const bf16x8*)(&KpB[(w * 16 + l16) * 64 + kg]);
#pragma unroll
        for (int nt = 0; nt < 4; ++nt) {
          bf16x8 bv8 = *(const bf16x8*)(&VtsB[cur * 4096 + (nt * 16 + l16) * 64 + kg]);
          pzacc[nt] = MFMA16(ak, bv8, pzacc[nt]);
        }
      }
    }
  }
}

extern "C" void kernel_launch(void* const* d_in, const int* in_sizes, int n_in,
                              void* d_out, int out_size, void* d_ws, size_t ws_size,
                              hipStream_t stream) {
  const float* Xq = (const float*)d_in[0];
  const float* Xk = (const float*)d_in[1];
  const float* Xv = (const float*)d_in[2];
  // d_in[3]: causal mask (int32) — tril, handled analytically
  const float* Wq = (const float*)d_in[4];
  const float* bq = (const float*)d_in[5];
  const float* Wk = (const float*)d_in[6];
  const float* bk = (const float*)d_in[7];
  const float* Wv = (const float*)d_in[8];
  const float* bv = (const float*)d_in[9];
  const float* Wo = (const float*)d_in[10];
  const float* bo = (const float*)d_in[11];

  // ws (MiB): [0,16) Q | [16,32) Kt | [32,48) Vt | [48,64) O | [64,66) WoB |
  // [66,66.5) R f32
  constexpr size_t MiB = 1024 * 1024;
  char* ws = (char*)d_ws;
  ushort_t* Qb  = (ushort_t*)(ws);
  ushort_t* Ktb = (ushort_t*)(ws + 16 * MiB);
  ushort_t* Vtb = (ushort_t*)(ws + 32 * MiB);
  ushort_t* Ob  = (ushort_t*)(ws + 48 * MiB);
  ushort_t* WoB = (ushort_t*)(ws + 64 * MiB);
  float*    Rsum= (float*)   (ws + 66 * MiB);

  qkv_f32<<<dim3(64, 8, 3), 256, 0, stream>>>(Xq, Xk, Xv, Wq, Wk, Wv,
                                              bq, bk, bv, Qb, Ktb, Vtb, Rsum);
  scan_attn2<<<dim3(64, 8), 256, 0, stream>>>(Qb, Ktb, Vtb, Rsum, Wo, WoB, Ob);
  gemm_out<<<dim3(64, 8), 256, 0, stream>>>(Ob, WoB, bo, (float*)d_out);
}

// Round 10
// 298.457 us; speedup vs baseline: 2.2520x; 2.2520x over previous
//
#include <hip/hip_runtime.h>
#include <stdint.h>

typedef unsigned short ushort_t;
typedef __bf16 bf16x8 __attribute__((ext_vector_type(8)));
typedef float f32x4 __attribute__((ext_vector_type(4)));
typedef ushort_t us4 __attribute__((ext_vector_type(4)));

#define MFMA16(a, b, c) __builtin_amdgcn_mfma_f32_16x16x32_bf16((a), (b), (c), 0, 0, 0)

constexpr int Bn = 4, Sn = 2048, Dn = 1024, Hn = 16, HDn = 64;
constexpr float SCALE = 0.125f;   // 1/sqrt(64)
constexpr float NEG = -1e9f;

__device__ __forceinline__ ushort_t f2bf(float f) {
  unsigned x = __builtin_bit_cast(unsigned, f);
  x = x + 0x7FFFu + ((x >> 16) & 1u);   // RNE
  return (ushort_t)(x >> 16);
}
// 8 x f32 -> bf16x8 via compiler (v_cvt_pk_bf16_f32, RNE — same bits as f2bf)
__device__ __forceinline__ bf16x8 cvt8(float4 a, float4 b) {
  bf16x8 r;
  r[0] = (__bf16)a.x; r[1] = (__bf16)a.y; r[2] = (__bf16)a.z; r[3] = (__bf16)a.w;
  r[4] = (__bf16)b.x; r[5] = (__bf16)b.y; r[6] = (__bf16)b.z; r[7] = (__bf16)b.w;
  return r;
}
// async global->LDS, 16B per lane; LDS dest = wave-uniform base + lane*16
__device__ __forceinline__ void gl2lds16(const void* g, void* l) {
  __builtin_amdgcn_global_load_lds(
      (__attribute__((address_space(1))) void*)g,
      (__attribute__((address_space(3))) void*)l, 16, 0, 0);
}

// f32 -> bf16 conversion, 16 elems/thread as TWO independent load->cvt_pk->
// store chains (ILP=2; the old 1-chunk/3-VALU-per-elem version ran at
// 2.3 TB/s, issue-bound). X: 6144 blocks (2048/matrix); W: 1024 (256/matrix).
__global__ __launch_bounds__(256)
void cvt_all(const float* __restrict__ xq, const float* __restrict__ xk,
             const float* __restrict__ xv, const float* __restrict__ wq,
             const float* __restrict__ wk, const float* __restrict__ wv,
             const float* __restrict__ wo, ushort_t* __restrict__ Xd,
             ushort_t* __restrict__ Wd) {
  const int bid = blockIdx.x;
  const float* s;
  ushort_t* d;
  size_t i;
  if (bid < 6144) {
    const int which = bid >> 11;
    s = which == 0 ? xq : which == 1 ? xk : xv;
    d = Xd + (size_t)which * 8388608;
    i = ((size_t)(bid & 2047) * 256 + threadIdx.x) * 16;
  } else {
    const int wb = bid - 6144, which = wb >> 8;
    s = which == 0 ? wq : which == 1 ? wk : which == 2 ? wv : wo;
    d = Wd + (size_t)which * 1048576;
    i = ((size_t)(wb & 255) * 256 + threadIdx.x) * 16;
  }
  float4 a = *(const float4*)(s + i);
  float4 b = *(const float4*)(s + i + 4);
  float4 c = *(const float4*)(s + i + 8);
  float4 e = *(const float4*)(s + i + 12);
  *(bf16x8*)(d + i)     = cvt8(a, b);
  *(bf16x8*)(d + i + 8) = cvt8(c, e);
}

// Fused Q/K/V projections (proven 63.5 us). z = 0/1/2 selects X, W, bias,
// dst, epilogue; z=2 also emits per-tile V row-sums R (f32, no atomics).
// z=0: Q scatter [B,H,S,HD]. z=1,2: transposed scatter [B,H,HD,S] b64.
__global__ __launch_bounds__(256, 4)
void gemm_qkv(const ushort_t* __restrict__ Xb, const ushort_t* __restrict__ Wb,
              const float* __restrict__ bq, const float* __restrict__ bk,
              const float* __restrict__ bv, ushort_t* __restrict__ Qd,
              ushort_t* __restrict__ Ktd, ushort_t* __restrict__ Vtd,
              float* __restrict__ Rs) {
  constexpr int K = 1024;
  __shared__ __align__(16) ushort_t As[128 * 64];
  __shared__ __align__(16) ushort_t Bs[128 * 64];

  const int z = blockIdx.z;
  const ushort_t* A  = Xb + (size_t)z * 8388608;
  const ushort_t* Wt = Wb + (size_t)z * 1048576;
  const float* bias = z == 0 ? bq : z == 1 ? bk : bv;
  ushort_t* Cp = z == 0 ? Qd : z == 1 ? Ktd : Vtd;

  const int tid = threadIdx.x;
  const int lane = tid & 63, w = tid >> 6;
  const int quad = lane >> 4, l16 = lane & 15;
  const int wm = w >> 1, wn = w & 1;
  const int row0 = blockIdx.x * 128;
  const int col0 = blockIdx.y * 128;

  const int sr = lane >> 3;
  const int sg = ((lane & 7) ^ (sr & 7)) * 8;
  const ushort_t* Ab = A  + (size_t)(row0 + w * 32 + sr) * K + sg;
  const ushort_t* Bb = Wt + (size_t)(col0 + w * 32 + sr) * K + sg;

  f32x4 acc[4][4] = {};

  for (int k0 = 0; k0 < K; k0 += 64) {
    __syncthreads();
#pragma unroll
    for (int i = 0; i < 4; ++i) {
      gl2lds16(Ab + (size_t)(i * 8) * K + k0, &As[(w * 32 + i * 8) * 64]);
      gl2lds16(Bb + (size_t)(i * 8) * K + k0, &Bs[(w * 32 + i * 8) * 64]);
    }
    __syncthreads();
#pragma unroll
    for (int ks = 0; ks < 2; ++ks) {
      const int kg = ((ks * 4 + quad) ^ (l16 & 7)) * 8;
      bf16x8 af[4], bfr[4];
#pragma unroll
      for (int mt = 0; mt < 4; ++mt)
        af[mt] = *(const bf16x8*)(&As[(wm * 64 + mt * 16 + l16) * 64 + kg]);
#pragma unroll
      for (int nt = 0; nt < 4; ++nt)
        bfr[nt] = *(const bf16x8*)(&Bs[(wn * 64 + nt * 16 + l16) * 64 + kg]);
#pragma unroll
      for (int mt = 0; mt < 4; ++mt)
#pragma unroll
        for (int nt = 0; nt < 4; ++nt)
          acc[mt][nt] = MFMA16(af[mt], bfr[nt], acc[mt][nt]);
    }
  }

#pragma unroll
  for (int mt = 0; mt < 4; ++mt) {
#pragma unroll
    for (int nt = 0; nt < 4; ++nt) {
      const int col = col0 + wn * 64 + nt * 16 + l16;
      const float bv4 = bias[col];
      const int rowb = row0 + wm * 64 + mt * 16 + quad * 4;
      if (z != 0) {          // transposed scatter: [b,h,hd,s], b64 over s
        const int b = rowb >> 11, s = rowb & (Sn - 1);
        const int h = col >> 6, hd = col & 63;
        us4 pk;
#pragma unroll
        for (int r = 0; r < 4; ++r) pk[r] = f2bf(acc[mt][nt][r] + bv4);
        *(us4*)(Cp + ((size_t)((b * Hn + h) * HDn + hd)) * Sn + s) = pk;
      } else {               // Q scatter: [b,h,s,hd]
#pragma unroll
        for (int r = 0; r < 4; ++r) {
          const int row = rowb + r;
          const int b = row >> 11, s = row & (Sn - 1);
          const int h = col >> 6, hd = col & 63;
          Cp[(((size_t)(b * Hn + h) * Sn + s) << 6) + hd] = f2bf(acc[mt][nt][r] + bv4);
        }
      }
    }
  }

  if (z == 2) {   // V tile row-sums: R[bh][t][n], t = wm-half (full 64 rows)
    const int b = row0 >> 11;
    const int t = ((row0 & (Sn - 1)) >> 6) + wm;
#pragma unroll
    for (int nt = 0; nt < 4; ++nt) {
      const int col = col0 + wn * 64 + nt * 16 + l16;
      const float bv4 = bias[col];
      float p = 0.f;
#pragma unroll
      for (int mt = 0; mt < 4; ++mt)
#pragma unroll
        for (int r = 0; r < 4; ++r) p += acc[mt][nt][r] + bv4;
      p += __shfl_xor(p, 16);
      p += __shfl_xor(p, 32);
      if (quad == 0) {
        const int h = col >> 6, n = col & 63;
        Rs[((size_t)(b * Hn + h) * 32 + t) * 64 + n] = p;
      }
    }
  }
}

// Final projection: C[M,N] f32 = A[M,K]bf16 @ W[N,K]^T + bias.
__global__ __launch_bounds__(256, 4)
void gemm_out(const ushort_t* __restrict__ A, const ushort_t* __restrict__ Wt,
              const float* __restrict__ bias, float* __restrict__ Cp) {
  constexpr int K = 1024;
  __shared__ __align__(16) ushort_t As[128 * 64];
  __shared__ __align__(16) ushort_t Bs[128 * 64];

  const int tid = threadIdx.x;
  const int lane = tid & 63, w = tid >> 6;
  const int quad = lane >> 4, l16 = lane & 15;
  const int wm = w >> 1, wn = w & 1;
  const int row0 = blockIdx.x * 128;
  const int col0 = blockIdx.y * 128;

  const int sr = lane >> 3;
  const int sg = ((lane & 7) ^ (sr & 7)) * 8;
  const ushort_t* Ab = A  + (size_t)(row0 + w * 32 + sr) * K + sg;
  const ushort_t* Bb = Wt + (size_t)(col0 + w * 32 + sr) * K + sg;

  f32x4 acc[4][4] = {};

  for (int k0 = 0; k0 < K; k0 += 64) {
    __syncthreads();
#pragma unroll
    for (int i = 0; i < 4; ++i) {
      gl2lds16(Ab + (size_t)(i * 8) * K + k0, &As[(w * 32 + i * 8) * 64]);
      gl2lds16(Bb + (size_t)(i * 8) * K + k0, &Bs[(w * 32 + i * 8) * 64]);
    }
    __syncthreads();
#pragma unroll
    for (int ks = 0; ks < 2; ++ks) {
      const int kg = ((ks * 4 + quad) ^ (l16 & 7)) * 8;
      bf16x8 af[4], bfr[4];
#pragma unroll
      for (int mt = 0; mt < 4; ++mt)
        af[mt] = *(const bf16x8*)(&As[(wm * 64 + mt * 16 + l16) * 64 + kg]);
#pragma unroll
      for (int nt = 0; nt < 4; ++nt)
        bfr[nt] = *(const bf16x8*)(&Bs[(wn * 64 + nt * 16 + l16) * 64 + kg]);
#pragma unroll
      for (int mt = 0; mt < 4; ++mt)
#pragma unroll
        for (int nt = 0; nt < 4; ++nt)
          acc[mt][nt] = MFMA16(af[mt], bfr[nt], acc[mt][nt]);
    }
  }

#pragma unroll
  for (int mt = 0; mt < 4; ++mt)
#pragma unroll
    for (int nt = 0; nt < 4; ++nt) {
      const int col = col0 + wn * 64 + nt * 16 + l16;
      const float bv = bias[col];
      const int rowb = row0 + wm * 64 + mt * 16 + quad * 4;
#pragma unroll
      for (int r = 0; r < 4; ++r)
        Cp[(size_t)(rowb + r) * 1024 + col] = acc[mt][nt][r] + bv;
    }
}

// Self-prefix attention. Grid (x=bh 64, y=g 8): block (bh,g) owns q-tiles
// 4g..4g+3. Prefix Z lives only in the MFMA accumulator. LDS 50 KB
// (Zs aliased onto prefix buffer Kp1; lifetimes disjoint) -> 3 blocks/CU.
__global__ __launch_bounds__(256)
void scan_attn2(const ushort_t* __restrict__ Q, const ushort_t* __restrict__ Kt,
                const ushort_t* __restrict__ Vt, const float* __restrict__ Rs,
                ushort_t* __restrict__ O) {
  // [0,8192) Kp0 (prefix dbuf 0; diag-K A-layout in attn)
  // [8192,16384) Kp1 (prefix dbuf 1) / Zs (attn)
  // [16384,32768) Vts[2]   [32768,40960) Ks
  // [40960,50176) Ss[64][72]   [50176,51200) sfx[4][64]
  __shared__ __align__(16) char smem[51200];
  ushort_t* KpB  = (ushort_t*)smem;
  ushort_t* Zs   = (ushort_t*)(smem + 8192);
  ushort_t* VtsB = (ushort_t*)(smem + 16384);
  ushort_t* Ks   = (ushort_t*)(smem + 32768);
  ushort_t (*Ss)[72] = (ushort_t(*)[72])(smem + 40960);
  float (*sfx)[64] = (float(*)[64])(smem + 50176);

  const int tid = threadIdx.x, lane = tid & 63, w = tid >> 6;
  const int quad = lane >> 4, l16 = lane & 15;
  const int bh = blockIdx.x;           // 0..63
  const int g = blockIdx.y;            // 0..7, q-tiles 4g..4g+3
  const int qt0 = g * 4;
  const int b = bh >> 4, h = bh & 15;
  const ushort_t* Qb  = Q  + (size_t)bh * Sn * HDn;
  const ushort_t* Ktb = Kt + (size_t)bh * HDn * Sn;
  const ushort_t* Vtb = Vt + (size_t)bh * HDn * Sn;
  const float* Rb = Rs + (size_t)bh * 32 * 64;

  const int sr = lane >> 3;
  const int sg = ((lane & 7) ^ (sr & 7)) * 8;
  const int q8 = lane & 7, h8 = lane >> 3;

  // ---- prefix phase: pzacc = sum_{tau<qt0} K_tau (x) V_tau (MFMA C-layout:
  // pzacc[nt][r] = Z[d = w*16+quad*4+r][n = nt*16+l16]) ----
  f32x4 pzacc[4] = {};
  if (qt0 > 0) {
#pragma unroll
    for (int c = 0; c < 2; ++c) {
      const int row = w * 16 + c * 8;
      gl2lds16(Ktb + (size_t)(row + sr) * Sn + sg, &KpB[row * 64]);
      gl2lds16(Vtb + (size_t)(row + sr) * Sn + sg, &VtsB[row * 64]);
    }
    for (int tau = 0; tau < qt0; ++tau) {
      const int pc = tau & 1;
      __syncthreads();                 // staging of buf[pc] drained
      if (tau + 1 < qt0) {             // prefetch tau+1 into other buffer
#pragma unroll
        for (int c = 0; c < 2; ++c) {
          const int row = w * 16 + c * 8;
          gl2lds16(Ktb + (size_t)(row + sr) * Sn + (tau + 1) * 64 + sg,
                   &KpB[(1 - pc) * 4096 + row * 64]);
          gl2lds16(Vtb + (size_t)(row + sr) * Sn + (tau + 1) * 64 + sg,
                   &VtsB[(1 - pc) * 4096 + row * 64]);
        }
      }
#pragma unroll
      for (int ks = 0; ks < 2; ++ks) {
        const int kg = ((ks * 4 + quad) ^ (l16 & 7)) * 8;
        bf16x8 ak = *(const bf16x8*)(&KpB[pc * 4096 + (w * 16 + l16) * 64 + kg]);
#pragma unroll
        for (int nt = 0; nt < 4; ++nt) {
          bf16x8 bv8 = *(const bf16x8*)(&VtsB[pc * 4096 + (nt * 16 + l16) * 64 + kg]);
          pzacc[nt] = MFMA16(ak, bv8, pzacc[nt]);
        }
      }
    }
    __syncthreads();                   // last prefix reads done before reuse
  }

  // ---- attn prologue: stage q-tile qt0 ----
  uint4  kvr[2][2];
  bf16x8 bqr[2][2];
  {
    const int q0 = qt0 * 64;
#pragma unroll
    for (int c = 0; c < 2; ++c) {
      const int row = w * 16 + c * 8;
      gl2lds16(Vtb + (size_t)(row + sr) * Sn + q0 + sg, &VtsB[row * 64]);
      kvr[0][c] = *(const uint4*)(Ktb + (size_t)(w * 16 + c * 8 + h8) * Sn + q0 + q8 * 8);
    }
#pragma unroll
    for (int ks = 0; ks < 2; ++ks)
      bqr[0][ks] = *(const bf16x8*)(Qb + (size_t)(q0 + w * 16 + l16) * HDn + (ks * 4 + quad) * 8);
  }

  // local suffix-V: sfx[i][n] = sum_{tau > qt0+i} R[tau][n]
  if (tid < 64) {
    float acc = 0.f;
    for (int tau = 31; tau >= qt0; --tau) {
      if (tau < qt0 + 4) sfx[tau - qt0][tid] = acc;
      acc += Rb[(size_t)tau * 64 + tid];
    }
  }

#pragma unroll 4
  for (int i = 0; i < 4; ++i) {
    const int cur = i & 1;
    const int qt = qt0 + i, q0 = qt * 64;

    __syncthreads();   // B1: compute i-1 done (Zs/Ks/Kp0 free); i=0: sfx cover

    // write Z for this q-tile from pzacc (MFMA layout) into swizzled Zs[n][d]
#pragma unroll
    for (int nt = 0; nt < 4; ++nt) {
      const int n = nt * 16 + l16;
      const int d0 = w * 16 + quad * 4;
      us4 pk;
#pragma unroll
      for (int r = 0; r < 4; ++r) pk[r] = f2bf(SCALE * pzacc[nt][r]);
      *(us4*)(&Zs[n * 64 + (((d0 >> 3) ^ (n & 7)) << 3) + (d0 & 7)]) = pk;
    }
    // transpose-write diagonal K tile (regs -> Ks, rotated+swizzled)
#pragma unroll
    for (int c = 0; c < 2; ++c) {
      const int hd = w * 16 + c * 8 + h8;
      const int G = hd >> 3;
      const ushort_t* ku = (const ushort_t*)&kvr[cur][c];
#pragma unroll
      for (int j = 0; j < 8; ++j) {
        const int e = (j + q8) & 7;
        const int s = q8 * 8 + e;
        Ks[s * 64 + ((G ^ e) << 3) + (hd & 7)] = ku[e];
      }
    }
    // diag K ALSO in standard A-layout (for the Z advance): Kp0
#pragma unroll
    for (int c = 0; c < 2; ++c) {
      const int hd = w * 16 + c * 8 + h8;
      *(uint4*)(&KpB[hd * 64 + ((q8 ^ (hd & 7)) << 3)]) = kvr[cur][c];
    }

    __syncthreads();   // B2: ds_writes visible + V(qt) staging drained

    if (i < 3) {       // issue next-tile loads; fly under compute(i)
      const int q1 = (qt + 1) * 64, nxt = 1 - cur;
#pragma unroll
      for (int c = 0; c < 2; ++c) {
        const int row = w * 16 + c * 8;
        gl2lds16(Vtb + (size_t)(row + sr) * Sn + q1 + sg, &VtsB[nxt * 4096 + row * 64]);
        kvr[nxt][c] = *(const uint4*)(Ktb + (size_t)(w * 16 + c * 8 + h8) * Sn + q1 + q8 * 8);
      }
#pragma unroll
      for (int ks = 0; ks < 2; ++ks)
        bqr[nxt][ks] = *(const bf16x8*)(Qb + (size_t)(q1 + w * 16 + l16) * HDn + (ks * 4 + quad) * 8);
    }

    // ---- compute q-tile qt ----
    f32x4 oacc[4] = {};
#pragma unroll
    for (int ks = 0; ks < 2; ++ks) {        // prefix: O^T += Z' · Q^T
      const int kg = ((ks * 4 + quad) ^ (l16 & 7)) * 8;
#pragma unroll
      for (int nt = 0; nt < 4; ++nt) {
        bf16x8 az = *(const bf16x8*)(&Zs[(nt * 16 + l16) * 64 + kg]);
        oacc[nt] = MFMA16(az, bqr[cur][ks], oacc[nt]);
      }
    }
    f32x4 sacc[4] = {};
#pragma unroll
    for (int ks = 0; ks < 2; ++ks) {        // diagonal: S^T = K_d · Q^T
      const int kg = ((ks * 4 + quad) ^ (l16 & 7)) * 8;
#pragma unroll
      for (int nt = 0; nt < 4; ++nt) {
        bf16x8 ak = *(const bf16x8*)(&Ks[(nt * 16 + l16) * 64 + kg]);
        sacc[nt] = MFMA16(ak, bqr[cur][ks], sacc[nt]);
      }
    }
    const int qrel = w * 16 + l16;          // mask + scale -> Ss (b64, intra-wave)
#pragma unroll
    for (int nt = 0; nt < 4; ++nt) {
      const int kb = nt * 16 + quad * 4;
      us4 pk;
#pragma unroll
      for (int r = 0; r < 4; ++r) {
        float val = (kb + r > qrel) ? NEG : sacc[nt][r] * SCALE;
        pk[r] = f2bf(val);
      }
      *(us4*)(&Ss[qrel][kb]) = pk;
    }
#pragma unroll
    for (int ks = 0; ks < 2; ++ks) {        // O^T += V_d^T · S_d^T
      bf16x8 bs = *(const bf16x8*)(&Ss[qrel][ks * 32 + quad * 8]);
#pragma unroll
      for (int nt = 0; nt < 4; ++nt) {
        bf16x8 av = *(const bf16x8*)(&VtsB[cur * 4096 + (nt * 16 + l16) * 64 + (((ks * 4 + quad) ^ (l16 & 7)) << 3)]);
        oacc[nt] = MFMA16(av, bs, oacc[nt]);
      }
    }

    // masked tail + store O[b,s,d] (b64 over n)
    const int s = q0 + w * 16 + l16;
#pragma unroll
    for (int nt = 0; nt < 4; ++nt) {
      const int nb = nt * 16 + quad * 4;
      float4 s4 = *(const float4*)(&sfx[i][nb]);
      us4 pk;
      pk[0] = f2bf(oacc[nt][0] + NEG * s4.x);
      pk[1] = f2bf(oacc[nt][1] + NEG * s4.y);
      pk[2] = f2bf(oacc[nt][2] + NEG * s4.z);
      pk[3] = f2bf(oacc[nt][3] + NEG * s4.w);
      *(us4*)(&O[((size_t)(b * Sn + s)) * Dn + h * 64 + nb]) = pk;
    }

    if (i < 3) {   // advance prefix: pzacc += K_qt (x) V_qt (diag tile)
#pragma unroll
      for (int ks = 0; ks < 2; ++ks) {
        const int kg = ((ks * 4 + quad) ^ (l16 & 7)) * 8;
        bf16x8 ak = *(const bf16x8*)(&KpB[(w * 16 + l16) * 64 + kg]);
#pragma unroll
        for (int nt = 0; nt < 4; ++nt) {
          bf16x8 bv8 = *(const bf16x8*)(&VtsB[cur * 4096 + (nt * 16 + l16) * 64 + kg]);
          pzacc[nt] = MFMA16(ak, bv8, pzacc[nt]);
        }
      }
    }
  }
}

extern "C" void kernel_launch(void* const* d_in, const int* in_sizes, int n_in,
                              void* d_out, int out_size, void* d_ws, size_t ws_size,
                              hipStream_t stream) {
  const float* Xq = (const float*)d_in[0];
  const float* Xk = (const float*)d_in[1];
  const float* Xv = (const float*)d_in[2];
  // d_in[3]: causal mask (int32) — tril, handled analytically
  const float* Wq = (const float*)d_in[4];
  const float* bq = (const float*)d_in[5];
  const float* Wk = (const float*)d_in[6];
  const float* bk = (const float*)d_in[7];
  const float* Wv = (const float*)d_in[8];
  const float* bv = (const float*)d_in[9];
  const float* Wo = (const float*)d_in[10];
  const float* bo = (const float*)d_in[11];

  // ws (MiB): [0,48) Xb(3) | [48,56) Wb(4) | [56,72) Q | [72,88) Kt |
  // [88,104) Vt | [120,136) O | [176,176.5) R f32
  constexpr size_t MiB = 1024 * 1024;
  char* ws = (char*)d_ws;
  ushort_t* Xb  = (ushort_t*)(ws);
  ushort_t* Wb  = (ushort_t*)(ws + 48 * MiB);
  ushort_t* Qb  = (ushort_t*)(ws + 56 * MiB);
  ushort_t* Ktb = (ushort_t*)(ws + 72 * MiB);
  ushort_t* Vtb = (ushort_t*)(ws + 88 * MiB);
  ushort_t* Ob  = (ushort_t*)(ws + 120 * MiB);
  float*    Rsum= (float*)   (ws + 176 * MiB);

  cvt_all<<<7168, 256, 0, stream>>>(Xq, Xk, Xv, Wq, Wk, Wv, Wo, Xb, Wb);
  gemm_qkv<<<dim3(64, 8, 3), 256, 0, stream>>>(Xb, Wb, bq, bk, bv, Qb, Ktb,
                                               Vtb, Rsum);
  scan_attn2<<<dim3(64, 8), 256, 0, stream>>>(Qb, Ktb, Vtb, Rsum, Ob);
  gemm_out<<<dim3(64, 8), 256, 0, stream>>>(Ob, Wb + (size_t)3 * 1048576, bo,
                                            (float*)d_out);
}

// Round 11
// 288.421 us; speedup vs baseline: 2.3304x; 1.0348x over previous
//
#include <hip/hip_runtime.h>
#include <stdint.h>

typedef unsigned short ushort_t;
typedef __bf16 bf16x8 __attribute__((ext_vector_type(8)));
typedef float f32x4 __attribute__((ext_vector_type(4)));
typedef ushort_t us4 __attribute__((ext_vector_type(4)));

#define MFMA16(a, b, c) __builtin_amdgcn_mfma_f32_16x16x32_bf16((a), (b), (c), 0, 0, 0)

constexpr int Bn = 4, Sn = 2048, Dn = 1024, Hn = 16, HDn = 64;
constexpr float SCALE = 0.125f;   // 1/sqrt(64)
constexpr float NEG = -1e9f;

__device__ __forceinline__ float bf2f(ushort_t u) {
  unsigned x = ((unsigned)u) << 16;
  return __builtin_bit_cast(float, x);
}
__device__ __forceinline__ ushort_t f2bf(float f) {
  unsigned x = __builtin_bit_cast(unsigned, f);
  x = x + 0x7FFFu + ((x >> 16) & 1u);   // RNE
  return (ushort_t)(x >> 16);
}
__device__ __forceinline__ uint4 ld8_f32_bf16(const float* __restrict__ p) {
  float4 a = *(const float4*)p;
  float4 b = *(const float4*)(p + 4);
  union { ushort_t u[8]; uint4 v; } r;
  r.u[0] = f2bf(a.x); r.u[1] = f2bf(a.y); r.u[2] = f2bf(a.z); r.u[3] = f2bf(a.w);
  r.u[4] = f2bf(b.x); r.u[5] = f2bf(b.y); r.u[6] = f2bf(b.z); r.u[7] = f2bf(b.w);
  return r.v;
}
// async global->LDS, 16B per lane; LDS dest = wave-uniform base + lane*16
__device__ __forceinline__ void gl2lds16(const void* g, void* l) {
  __builtin_amdgcn_global_load_lds(
      (__attribute__((address_space(1))) void*)g,
      (__attribute__((address_space(3))) void*)l, 16, 0, 0);
}

// One-shot conversion of all f32 inputs to bf16 (r7 total-best variant:
// 8 elems/thread, lane-coalesced 32B loads / 16B stores, 14336 blocks).
// Cost is dominated by the unavoidable cold first-touch of the inputs.
__global__ __launch_bounds__(256)
void cvt_all(const float* __restrict__ xq, const float* __restrict__ xk,
             const float* __restrict__ xv, const float* __restrict__ wq,
             const float* __restrict__ wk, const float* __restrict__ wv,
             const float* __restrict__ wo, ushort_t* __restrict__ Xd,
             ushort_t* __restrict__ Wd) {
  const int bid = blockIdx.x;
  if (bid < 12288) {
    const int which = bid >> 12;
    const float* s = which == 0 ? xq : which == 1 ? xk : xv;
    size_t i = ((size_t)(bid & 4095) * 256 + threadIdx.x) * 8;
    *(uint4*)(Xd + (size_t)which * 8388608 + i) = ld8_f32_bf16(s + i);
  } else {
    const int wb = bid - 12288, which = wb >> 9;
    const float* s = which == 0 ? wq : which == 1 ? wk : which == 2 ? wv : wo;
    size_t i = ((size_t)(wb & 511) * 256 + threadIdx.x) * 8;
    *(uint4*)(Wd + (size_t)which * 1048576 + i) = ld8_f32_bf16(s + i);
  }
}

// Fused Q/K/V projections (proven 63.5 us; 811 TF ~ 95% of the measured
// K=1024 structural ceiling). z = 0/1/2 selects X, W, bias, dst, epilogue;
// z=2 also emits per-tile V row-sums R (f32, no atomics).
__global__ __launch_bounds__(256, 4)
void gemm_qkv(const ushort_t* __restrict__ Xb, const ushort_t* __restrict__ Wb,
              const float* __restrict__ bq, const float* __restrict__ bk,
              const float* __restrict__ bv, ushort_t* __restrict__ Qd,
              ushort_t* __restrict__ Ktd, ushort_t* __restrict__ Vtd,
              float* __restrict__ Rs) {
  constexpr int K = 1024;
  __shared__ __align__(16) ushort_t As[128 * 64];
  __shared__ __align__(16) ushort_t Bs[128 * 64];

  const int z = blockIdx.z;
  const ushort_t* A  = Xb + (size_t)z * 8388608;
  const ushort_t* Wt = Wb + (size_t)z * 1048576;
  const float* bias = z == 0 ? bq : z == 1 ? bk : bv;
  ushort_t* Cp = z == 0 ? Qd : z == 1 ? Ktd : Vtd;

  const int tid = threadIdx.x;
  const int lane = tid & 63, w = tid >> 6;
  const int quad = lane >> 4, l16 = lane & 15;
  const int wm = w >> 1, wn = w & 1;
  const int row0 = blockIdx.x * 128;
  const int col0 = blockIdx.y * 128;

  const int sr = lane >> 3;
  const int sg = ((lane & 7) ^ (sr & 7)) * 8;
  const ushort_t* Ab = A  + (size_t)(row0 + w * 32 + sr) * K + sg;
  const ushort_t* Bb = Wt + (size_t)(col0 + w * 32 + sr) * K + sg;

  f32x4 acc[4][4] = {};

  for (int k0 = 0; k0 < K; k0 += 64) {
    __syncthreads();
#pragma unroll
    for (int i = 0; i < 4; ++i) {
      gl2lds16(Ab + (size_t)(i * 8) * K + k0, &As[(w * 32 + i * 8) * 64]);
      gl2lds16(Bb + (size_t)(i * 8) * K + k0, &Bs[(w * 32 + i * 8) * 64]);
    }
    __syncthreads();
#pragma unroll
    for (int ks = 0; ks < 2; ++ks) {
      const int kg = ((ks * 4 + quad) ^ (l16 & 7)) * 8;
      bf16x8 af[4], bfr[4];
#pragma unroll
      for (int mt = 0; mt < 4; ++mt)
        af[mt] = *(const bf16x8*)(&As[(wm * 64 + mt * 16 + l16) * 64 + kg]);
#pragma unroll
      for (int nt = 0; nt < 4; ++nt)
        bfr[nt] = *(const bf16x8*)(&Bs[(wn * 64 + nt * 16 + l16) * 64 + kg]);
#pragma unroll
      for (int mt = 0; mt < 4; ++mt)
#pragma unroll
        for (int nt = 0; nt < 4; ++nt)
          acc[mt][nt] = MFMA16(af[mt], bfr[nt], acc[mt][nt]);
    }
  }

#pragma unroll
  for (int mt = 0; mt < 4; ++mt) {
#pragma unroll
    for (int nt = 0; nt < 4; ++nt) {
      const int col = col0 + wn * 64 + nt * 16 + l16;
      const float bv4 = bias[col];
      const int rowb = row0 + wm * 64 + mt * 16 + quad * 4;
      if (z != 0) {          // transposed scatter: [b,h,hd,s], b64 over s
        const int b = rowb >> 11, s = rowb & (Sn - 1);
        const int h = col >> 6, hd = col & 63;
        us4 pk;
#pragma unroll
        for (int r = 0; r < 4; ++r) pk[r] = f2bf(acc[mt][nt][r] + bv4);
        *(us4*)(Cp + ((size_t)((b * Hn + h) * HDn + hd)) * Sn + s) = pk;
      } else {               // Q scatter: [b,h,s,hd]
#pragma unroll
        for (int r = 0; r < 4; ++r) {
          const int row = rowb + r;
          const int b = row >> 11, s = row & (Sn - 1);
          const int h = col >> 6, hd = col & 63;
          Cp[(((size_t)(b * Hn + h) * Sn + s) << 6) + hd] = f2bf(acc[mt][nt][r] + bv4);
        }
      }
    }
  }

  if (z == 2) {   // V tile row-sums: R[bh][t][n], t = wm-half (full 64 rows)
    const int b = row0 >> 11;
    const int t = ((row0 & (Sn - 1)) >> 6) + wm;
#pragma unroll
    for (int nt = 0; nt < 4; ++nt) {
      const int col = col0 + wn * 64 + nt * 16 + l16;
      const float bv4 = bias[col];
      float p = 0.f;
#pragma unroll
      for (int mt = 0; mt < 4; ++mt)
#pragma unroll
        for (int r = 0; r < 4; ++r) p += acc[mt][nt][r] + bv4;
      p += __shfl_xor(p, 16);
      p += __shfl_xor(p, 32);
      if (quad == 0) {
        const int h = col >> 6, n = col & 63;
        Rs[((size_t)(b * Hn + h) * 32 + t) * 64 + n] = p;
      }
    }
  }
}

// Final projection: C[M,N] f32 = A[M,K]bf16 @ W[N,K]^T + bias.
__global__ __launch_bounds__(256, 4)
void gemm_out(const ushort_t* __restrict__ A, const ushort_t* __restrict__ Wt,
              const float* __restrict__ bias, float* __restrict__ Cp) {
  constexpr int K = 1024;
  __shared__ __align__(16) ushort_t As[128 * 64];
  __shared__ __align__(16) ushort_t Bs[128 * 64];

  const int tid = threadIdx.x;
  const int lane = tid & 63, w = tid >> 6;
  const int quad = lane >> 4, l16 = lane & 15;
  const int wm = w >> 1, wn = w & 1;
  const int row0 = blockIdx.x * 128;
  const int col0 = blockIdx.y * 128;

  const int sr = lane >> 3;
  const int sg = ((lane & 7) ^ (sr & 7)) * 8;
  const ushort_t* Ab = A  + (size_t)(row0 + w * 32 + sr) * K + sg;
  const ushort_t* Bb = Wt + (size_t)(col0 + w * 32 + sr) * K + sg;

  f32x4 acc[4][4] = {};

  for (int k0 = 0; k0 < K; k0 += 64) {
    __syncthreads();
#pragma unroll
    for (int i = 0; i < 4; ++i) {
      gl2lds16(Ab + (size_t)(i * 8) * K + k0, &As[(w * 32 + i * 8) * 64]);
      gl2lds16(Bb + (size_t)(i * 8) * K + k0, &Bs[(w * 32 + i * 8) * 64]);
    }
    __syncthreads();
#pragma unroll
    for (int ks = 0; ks < 2; ++ks) {
      const int kg = ((ks * 4 + quad) ^ (l16 & 7)) * 8;
      bf16x8 af[4], bfr[4];
#pragma unroll
      for (int mt = 0; mt < 4; ++mt)
        af[mt] = *(const bf16x8*)(&As[(wm * 64 + mt * 16 + l16) * 64 + kg]);
#pragma unroll
      for (int nt = 0; nt < 4; ++nt)
        bfr[nt] = *(const bf16x8*)(&Bs[(wn * 64 + nt * 16 + l16) * 64 + kg]);
#pragma unroll
      for (int mt = 0; mt < 4; ++mt)
#pragma unroll
        for (int nt = 0; nt < 4; ++nt)
          acc[mt][nt] = MFMA16(af[mt], bfr[nt], acc[mt][nt]);
    }
  }

#pragma unroll
  for (int mt = 0; mt < 4; ++mt)
#pragma unroll
    for (int nt = 0; nt < 4; ++nt) {
      const int col = col0 + wn * 64 + nt * 16 + l16;
      const float bv = bias[col];
      const int rowb = row0 + wm * 64 + mt * 16 + quad * 4;
#pragma unroll
      for (int r = 0; r < 4; ++r)
        Cp[(size_t)(rowb + r) * 1024 + col] = acc[mt][nt][r] + bv;
    }
}

// Self-prefix attention. Grid (x=bh 64, y=g 8). Prefix Z lives only in the
// MFMA accumulator; LDS 50 KB (Zs aliased onto prefix buffer Kp1) ->
// 3 blocks/CU. s_setprio(1) wraps the MFMA clusters (T5: heterogeneous
// block phases -> scheduler favors MFMA-issuing waves; attn-measured +4-7%).
__global__ __launch_bounds__(256)
void scan_attn2(const ushort_t* __restrict__ Q, const ushort_t* __restrict__ Kt,
                const ushort_t* __restrict__ Vt, const float* __restrict__ Rs,
                ushort_t* __restrict__ O) {
  // [0,8192) Kp0 (prefix dbuf 0; diag-K A-layout in attn)
  // [8192,16384) Kp1 (prefix dbuf 1) / Zs (attn)
  // [16384,32768) Vts[2]   [32768,40960) Ks
  // [40960,50176) Ss[64][72]   [50176,51200) sfx[4][64]
  __shared__ __align__(16) char smem[51200];
  ushort_t* KpB  = (ushort_t*)smem;
  ushort_t* Zs   = (ushort_t*)(smem + 8192);
  ushort_t* VtsB = (ushort_t*)(smem + 16384);
  ushort_t* Ks   = (ushort_t*)(smem + 32768);
  ushort_t (*Ss)[72] = (ushort_t(*)[72])(smem + 40960);
  float (*sfx)[64] = (float(*)[64])(smem + 50176);

  const int tid = threadIdx.x, lane = tid & 63, w = tid >> 6;
  const int quad = lane >> 4, l16 = lane & 15;
  const int bh = blockIdx.x;           // 0..63
  const int g = blockIdx.y;            // 0..7, q-tiles 4g..4g+3
  const int qt0 = g * 4;
  const int b = bh >> 4, h = bh & 15;
  const ushort_t* Qb  = Q  + (size_t)bh * Sn * HDn;
  const ushort_t* Ktb = Kt + (size_t)bh * HDn * Sn;
  const ushort_t* Vtb = Vt + (size_t)bh * HDn * Sn;
  const float* Rb = Rs + (size_t)bh * 32 * 64;

  const int sr = lane >> 3;
  const int sg = ((lane & 7) ^ (sr & 7)) * 8;
  const int q8 = lane & 7, h8 = lane >> 3;

  // ---- prefix phase: pzacc = sum_{tau<qt0} K_tau (x) V_tau (MFMA C-layout:
  // pzacc[nt][r] = Z[d = w*16+quad*4+r][n = nt*16+l16]) ----
  f32x4 pzacc[4] = {};
  if (qt0 > 0) {
#pragma unroll
    for (int c = 0; c < 2; ++c) {
      const int row = w * 16 + c * 8;
      gl2lds16(Ktb + (size_t)(row + sr) * Sn + sg, &KpB[row * 64]);
      gl2lds16(Vtb + (size_t)(row + sr) * Sn + sg, &VtsB[row * 64]);
    }
    for (int tau = 0; tau < qt0; ++tau) {
      const int pc = tau & 1;
      __syncthreads();                 // staging of buf[pc] drained
      if (tau + 1 < qt0) {             // prefetch tau+1 into other buffer
#pragma unroll
        for (int c = 0; c < 2; ++c) {
          const int row = w * 16 + c * 8;
          gl2lds16(Ktb + (size_t)(row + sr) * Sn + (tau + 1) * 64 + sg,
                   &KpB[(1 - pc) * 4096 + row * 64]);
          gl2lds16(Vtb + (size_t)(row + sr) * Sn + (tau + 1) * 64 + sg,
                   &VtsB[(1 - pc) * 4096 + row * 64]);
        }
      }
      __builtin_amdgcn_s_setprio(1);
#pragma unroll
      for (int ks = 0; ks < 2; ++ks) {
        const int kg = ((ks * 4 + quad) ^ (l16 & 7)) * 8;
        bf16x8 ak = *(const bf16x8*)(&KpB[pc * 4096 + (w * 16 + l16) * 64 + kg]);
#pragma unroll
        for (int nt = 0; nt < 4; ++nt) {
          bf16x8 bv8 = *(const bf16x8*)(&VtsB[pc * 4096 + (nt * 16 + l16) * 64 + kg]);
          pzacc[nt] = MFMA16(ak, bv8, pzacc[nt]);
        }
      }
      __builtin_amdgcn_s_setprio(0);
    }
    __syncthreads();                   // last prefix reads done before reuse
  }

  // ---- attn prologue: stage q-tile qt0 ----
  uint4  kvr[2][2];
  bf16x8 bqr[2][2];
  {
    const int q0 = qt0 * 64;
#pragma unroll
    for (int c = 0; c < 2; ++c) {
      const int row = w * 16 + c * 8;
      gl2lds16(Vtb + (size_t)(row + sr) * Sn + q0 + sg, &VtsB[row * 64]);
      kvr[0][c] = *(const uint4*)(Ktb + (size_t)(w * 16 + c * 8 + h8) * Sn + q0 + q8 * 8);
    }
#pragma unroll
    for (int ks = 0; ks < 2; ++ks)
      bqr[0][ks] = *(const bf16x8*)(Qb + (size_t)(q0 + w * 16 + l16) * HDn + (ks * 4 + quad) * 8);
  }

  // local suffix-V: sfx[i][n] = sum_{tau > qt0+i} R[tau][n]
  if (tid < 64) {
    float acc = 0.f;
    for (int tau = 31; tau >= qt0; --tau) {
      if (tau < qt0 + 4) sfx[tau - qt0][tid] = acc;
      acc += Rb[(size_t)tau * 64 + tid];
    }
  }

#pragma unroll 4
  for (int i = 0; i < 4; ++i) {
    const int cur = i & 1;
    const int qt = qt0 + i, q0 = qt * 64;

    __syncthreads();   // B1: compute i-1 done (Zs/Ks/Kp0 free); i=0: sfx cover

    // write Z for this q-tile from pzacc (MFMA layout) into swizzled Zs[n][d]
#pragma unroll
    for (int nt = 0; nt < 4; ++nt) {
      const int n = nt * 16 + l16;
      const int d0 = w * 16 + quad * 4;
      us4 pk;
#pragma unroll
      for (int r = 0; r < 4; ++r) pk[r] = f2bf(SCALE * pzacc[nt][r]);
      *(us4*)(&Zs[n * 64 + (((d0 >> 3) ^ (n & 7)) << 3) + (d0 & 7)]) = pk;
    }
    // transpose-write diagonal K tile (regs -> Ks, rotated+swizzled)
#pragma unroll
    for (int c = 0; c < 2; ++c) {
      const int hd = w * 16 + c * 8 + h8;
      const int G = hd >> 3;
      const ushort_t* ku = (const ushort_t*)&kvr[cur][c];
#pragma unroll
      for (int j = 0; j < 8; ++j) {
        const int e = (j + q8) & 7;
        const int s = q8 * 8 + e;
        Ks[s * 64 + ((G ^ e) << 3) + (hd & 7)] = ku[e];
      }
    }
    // diag K ALSO in standard A-layout (for the Z advance): Kp0
#pragma unroll
    for (int c = 0; c < 2; ++c) {
      const int hd = w * 16 + c * 8 + h8;
      *(uint4*)(&KpB[hd * 64 + ((q8 ^ (hd & 7)) << 3)]) = kvr[cur][c];
    }

    __syncthreads();   // B2: ds_writes visible + V(qt) staging drained

    if (i < 3) {       // issue next-tile loads; fly under compute(i)
      const int q1 = (qt + 1) * 64, nxt = 1 - cur;
#pragma unroll
      for (int c = 0; c < 2; ++c) {
        const int row = w * 16 + c * 8;
        gl2lds16(Vtb + (size_t)(row + sr) * Sn + q1 + sg, &VtsB[nxt * 4096 + row * 64]);
        kvr[nxt][c] = *(const uint4*)(Ktb + (size_t)(w * 16 + c * 8 + h8) * Sn + q1 + q8 * 8);
      }
#pragma unroll
      for (int ks = 0; ks < 2; ++ks)
        bqr[nxt][ks] = *(const bf16x8*)(Qb + (size_t)(q1 + w * 16 + l16) * HDn + (ks * 4 + quad) * 8);
    }

    // ---- compute q-tile qt ----
    f32x4 oacc[4] = {};
    __builtin_amdgcn_s_setprio(1);
#pragma unroll
    for (int ks = 0; ks < 2; ++ks) {        // prefix: O^T += Z' · Q^T
      const int kg = ((ks * 4 + quad) ^ (l16 & 7)) * 8;
#pragma unroll
      for (int nt = 0; nt < 4; ++nt) {
        bf16x8 az = *(const bf16x8*)(&Zs[(nt * 16 + l16) * 64 + kg]);
        oacc[nt] = MFMA16(az, bqr[cur][ks], oacc[nt]);
      }
    }
    f32x4 sacc[4] = {};
#pragma unroll
    for (int ks = 0; ks < 2; ++ks) {        // diagonal: S^T = K_d · Q^T
      const int kg = ((ks * 4 + quad) ^ (l16 & 7)) * 8;
#pragma unroll
      for (int nt = 0; nt < 4; ++nt) {
        bf16x8 ak = *(const bf16x8*)(&Ks[(nt * 16 + l16) * 64 + kg]);
        sacc[nt] = MFMA16(ak, bqr[cur][ks], sacc[nt]);
      }
    }
    __builtin_amdgcn_s_setprio(0);
    const int qrel = w * 16 + l16;          // mask + scale -> Ss (b64, intra-wave)
#pragma unroll
    for (int nt = 0; nt < 4; ++nt) {
      const int kb = nt * 16 + quad * 4;
      us4 pk;
#pragma unroll
      for (int r = 0; r < 4; ++r) {
        float val = (kb + r > qrel) ? NEG : sacc[nt][r] * SCALE;
        pk[r] = f2bf(val);
      }
      *(us4*)(&Ss[qrel][kb]) = pk;
    }
    __builtin_amdgcn_s_setprio(1);
#pragma unroll
    for (int ks = 0; ks < 2; ++ks) {        // O^T += V_d^T · S_d^T
      bf16x8 bs = *(const bf16x8*)(&Ss[qrel][ks * 32 + quad * 8]);
#pragma unroll
      for (int nt = 0; nt < 4; ++nt) {
        bf16x8 av = *(const bf16x8*)(&VtsB[cur * 4096 + (nt * 16 + l16) * 64 + (((ks * 4 + quad) ^ (l16 & 7)) << 3)]);
        oacc[nt] = MFMA16(av, bs, oacc[nt]);
      }
    }
    __builtin_amdgcn_s_setprio(0);

    // masked tail + store O[b,s,d] (b64 over n)
    const int s = q0 + w * 16 + l16;
#pragma unroll
    for (int nt = 0; nt < 4; ++nt) {
      const int nb = nt * 16 + quad * 4;
      float4 s4 = *(const float4*)(&sfx[i][nb]);
      us4 pk;
      pk[0] = f2bf(oacc[nt][0] + NEG * s4.x);
      pk[1] = f2bf(oacc[nt][1] + NEG * s4.y);
      pk[2] = f2bf(oacc[nt][2] + NEG * s4.z);
      pk[3] = f2bf(oacc[nt][3] + NEG * s4.w);
      *(us4*)(&O[((size_t)(b * Sn + s)) * Dn + h * 64 + nb]) = pk;
    }

    if (i < 3) {   // advance prefix: pzacc += K_qt (x) V_qt (diag tile)
      __builtin_amdgcn_s_setprio(1);
#pragma unroll
      for (int ks = 0; ks < 2; ++ks) {
        const int kg = ((ks * 4 + quad) ^ (l16 & 7)) * 8;
        bf16x8 ak = *(const bf16x8*)(&KpB[(w * 16 + l16) * 64 + kg]);
#pragma unroll
        for (int nt = 0; nt < 4; ++nt) {
          bf16x8 bv8 = *(const bf16x8*)(&VtsB[cur * 4096 + (nt * 16 + l16) * 64 + kg]);
          pzacc[nt] = MFMA16(ak, bv8, pzacc[nt]);
        }
      }
      __builtin_amdgcn_s_setprio(0);
    }
  }
}

extern "C" void kernel_launch(void* const* d_in, const int* in_sizes, int n_in,
                              void* d_out, int out_size, void* d_ws, size_t ws_size,
                              hipStream_t stream) {
  const float* Xq = (const float*)d_in[0];
  const float* Xk = (const float*)d_in[1];
  const float* Xv = (const float*)d_in[2];
  // d_in[3]: causal mask (int32) — tril, handled analytically
  const float* Wq = (const float*)d_in[4];
  const float* bq = (const float*)d_in[5];
  const float* Wk = (const float*)d_in[6];
  const float* bk = (const float*)d_in[7];
  const float* Wv = (const float*)d_in[8];
  const float* bv = (const float*)d_in[9];
  const float* Wo = (const float*)d_in[10];
  const float* bo = (const float*)d_in[11];

  // ws (MiB): [0,48) Xb(3) | [48,56) Wb(4) | [56,72) Q | [72,88) Kt |
  // [88,104) Vt | [120,136) O | [176,176.5) R f32
  constexpr size_t MiB = 1024 * 1024;
  char* ws = (char*)d_ws;
  ushort_t* Xb  = (ushort_t*)(ws);
  ushort_t* Wb  = (ushort_t*)(ws + 48 * MiB);
  ushort_t* Qb  = (ushort_t*)(ws + 56 * MiB);
  ushort_t* Ktb = (ushort_t*)(ws + 72 * MiB);
  ushort_t* Vtb = (ushort_t*)(ws + 88 * MiB);
  ushort_t* Ob  = (ushort_t*)(ws + 120 * MiB);
  float*    Rsum= (float*)   (ws + 176 * MiB);

  cvt_all<<<14336, 256, 0, stream>>>(Xq, Xk, Xv, Wq, Wk, Wv, Wo, Xb, Wb);
  gemm_qkv<<<dim3(64, 8, 3), 256, 0, stream>>>(Xb, Wb, bq, bk, bv, Qb, Ktb,
                                               Vtb, Rsum);
  scan_attn2<<<dim3(64, 8), 256, 0, stream>>>(Qb, Ktb, Vtb, Rsum, Ob);
  gemm_out<<<dim3(64, 8), 256, 0, stream>>>(Ob, Wb + (size_t)3 * 1048576, bo,
                                            (float*)d_out);
}